// Round 1
// baseline (328.087 us; speedup 1.0000x reference)
//
#include <hip/hip_runtime.h>
#include <math.h>

// B=16, L=200, H=256, heads=4, d=64
#define LQ 200
#define HDIM 256

// ---------------- Kernel 1: projections + pos-bias folding -------------------
// Q    = queries @ Wq.T + bq
// Ksum = keys    @ Wk.T + bk + abs_pos_K
// Vsum = keys    @ Wv.T + bv + abs_pos_V
// 400 blocks x 256 threads; each block does 8 rows, thread j owns output col j.
__global__ __launch_bounds__(256) void proj_kernel(
    const float* __restrict__ queries, const float* __restrict__ keys,
    const float* __restrict__ posK, const float* __restrict__ posV,
    const float* __restrict__ Wq, const float* __restrict__ bq,
    const float* __restrict__ Wk, const float* __restrict__ bk,
    const float* __restrict__ Wv, const float* __restrict__ bv,
    float* __restrict__ Qp, float* __restrict__ Ksum, float* __restrict__ Vsum)
{
    __shared__ float qrow[8][HDIM];
    __shared__ float krow[8][HDIM];
    const int t = threadIdx.x;
    const int blk = blockIdx.x;                 // 0..399
    const size_t base = (size_t)blk * 8 * HDIM;

    // stage 8 rows of queries & keys (2048 floats each), coalesced float4
    #pragma unroll
    for (int i = 0; i < 2; ++i) {
        int idx = i * 1024 + t * 4;
        *(float4*)&qrow[0][idx] = *(const float4*)&queries[base + idx];
        *(float4*)&krow[0][idx] = *(const float4*)&keys[base + idx];
    }
    __syncthreads();

    float accQ[8], accK[8], accV[8];
    #pragma unroll
    for (int r = 0; r < 8; ++r) { accQ[r] = 0.f; accK[r] = 0.f; accV[r] = 0.f; }

    const float4* wqp = (const float4*)&Wq[t * HDIM];
    const float4* wkp = (const float4*)&Wk[t * HDIM];
    const float4* wvp = (const float4*)&Wv[t * HDIM];

    for (int k4 = 0; k4 < HDIM / 4; ++k4) {
        float4 wq = wqp[k4], wk = wkp[k4], wv = wvp[k4];
        #pragma unroll
        for (int r = 0; r < 8; ++r) {
            float4 qv = *(const float4*)&qrow[r][k4 * 4];
            float4 kv = *(const float4*)&krow[r][k4 * 4];
            accQ[r] += qv.x * wq.x + qv.y * wq.y + qv.z * wq.z + qv.w * wq.w;
            accK[r] += kv.x * wk.x + kv.y * wk.y + kv.z * wk.z + kv.w * wk.w;
            accV[r] += kv.x * wv.x + kv.y * wv.y + kv.z * wv.z + kv.w * wv.w;
        }
    }

    const float bqv = bq[t], bkv = bk[t], bvv = bv[t];
    #pragma unroll
    for (int r = 0; r < 8; ++r) {
        size_t row = (size_t)blk * 8 + r;
        Qp[row * HDIM + t]   = accQ[r] + bqv;
        Ksum[row * HDIM + t] = accK[r] + bkv + posK[row * HDIM + t];
        Vsum[row * HDIM + t] = accV[r] + bvv + posV[row * HDIM + t];
    }
}

// ---------------- Kernel 2: scores + softmax + PV ---------------------------
// One block per (b,l). 256 threads = 4 waves.
// Thread t: wave w = t>>6, lane ln = t&63, head h = ln>>4, channel quad c = ln*4.
// Phase 1: per iter, wave w handles key m = it*4+w; block reads a full 1KB
//   row slice of tmK (coalesced f4) + Ksum; 16-lane shfl_xor reduces the dot.
// Phase 2: wave w does softmax of head-row w (causal + time_mask semantics).
// Phase 3: same layout as phase 1 streaming tmV + Vsum; 4 wave-partials
//   combined through LDS.
__global__ __launch_bounds__(256) void attn_kernel(
    const float* __restrict__ Qp, const float* __restrict__ Ksum,
    const float* __restrict__ Vsum, const float* __restrict__ tmK,
    const float* __restrict__ tmV, const int* __restrict__ tmask,
    float* __restrict__ out)
{
    __shared__ float sc[4][204];      // scores, then attention weights
    __shared__ float outp[4][HDIM];   // per-wave output partials

    const int t = threadIdx.x;
    const int w = t >> 6;
    const int ln = t & 63;
    const int h = ln >> 4;
    const int c = ln * 4;
    const int blk = blockIdx.x;       // b*200 + l
    const int b = blk / LQ;
    const int l = blk - b * LQ;

    const float* tmK_row = tmK + (size_t)blk * (LQ * HDIM);
    const float* tmV_row = tmV + (size_t)blk * (LQ * HDIM);
    const float* Ks_b = Ksum + (size_t)b * (LQ * HDIM);
    const float* Vs_b = Vsum + (size_t)b * (LQ * HDIM);
    const bool rowmask = (tmask[blk] != 0);

    const float4 Q4 = *(const float4*)&Qp[(size_t)blk * HDIM + c];

    // ---- Phase 1: scores ----
    for (int it = 0; it < LQ / 4; ++it) {
        const int m = it * 4 + w;
        float4 k1 = *(const float4*)&tmK_row[m * HDIM + c];
        float4 k2 = *(const float4*)&Ks_b[m * HDIM + c];
        float p = Q4.x * (k1.x + k2.x) + Q4.y * (k1.y + k2.y)
                + Q4.z * (k1.z + k2.z) + Q4.w * (k1.w + k2.w);
        p += __shfl_xor(p, 1);
        p += __shfl_xor(p, 2);
        p += __shfl_xor(p, 4);
        p += __shfl_xor(p, 8);
        if ((ln & 15) == 0) sc[h][m] = p;
    }
    __syncthreads();

    // ---- Phase 2: softmax (wave w owns head row w) ----
    {
        float sreg[4];
        float mx = -INFINITY;
        #pragma unroll
        for (int jj = 0; jj < 4; ++jj) {
            int m = ln + 64 * jj;
            if (m < LQ) {
                float s = sc[w][m] * 0.125f;   // 1/sqrt(64)
                sreg[jj] = s;
                if (m <= l) mx = fmaxf(mx, s);
            }
        }
        #pragma unroll
        for (int msk = 1; msk < 64; msk <<= 1) mx = fmaxf(mx, __shfl_xor(mx, msk));
        float e[4];
        float sum = 0.f;
        #pragma unroll
        for (int jj = 0; jj < 4; ++jj) {
            int m = ln + 64 * jj;
            float ev = 0.f;
            if (m < LQ && m <= l) ev = __expf(sreg[jj] - mx);
            e[jj] = ev;
            sum += ev;
        }
        #pragma unroll
        for (int msk = 1; msk < 64; msk <<= 1) sum += __shfl_xor(sum, msk);
        const float inv = 1.0f / sum;
        const float uni = 1.0f / (float)LQ;   // fully-masked row -> exact uniform
        #pragma unroll
        for (int jj = 0; jj < 4; ++jj) {
            int m = ln + 64 * jj;
            if (m < LQ) sc[w][m] = rowmask ? uni : (e[jj] * inv);
        }
    }
    __syncthreads();

    // ---- Phase 3: out = sum_m A[h][m] * (Vsum + tmV) ----
    float4 acc = {0.f, 0.f, 0.f, 0.f};
    for (int it = 0; it < LQ / 4; ++it) {
        const int m = it * 4 + w;
        const float a = sc[h][m];
        float4 v1 = *(const float4*)&tmV_row[m * HDIM + c];
        float4 v2 = *(const float4*)&Vs_b[m * HDIM + c];
        acc.x += a * (v1.x + v2.x);
        acc.y += a * (v1.y + v2.y);
        acc.z += a * (v1.z + v2.z);
        acc.w += a * (v1.w + v2.w);
    }
    *(float4*)&outp[w][c] = acc;
    __syncthreads();

    out[(size_t)blk * HDIM + t] = outp[0][t] + outp[1][t] + outp[2][t] + outp[3][t];
}

// ---------------- launch ----------------------------------------------------
extern "C" void kernel_launch(void* const* d_in, const int* in_sizes, int n_in,
                              void* d_out, int out_size, void* d_ws, size_t ws_size,
                              hipStream_t stream) {
    const float* queries = (const float*)d_in[0];
    const float* keys    = (const float*)d_in[1];
    const int*   tmask   = (const int*)d_in[2];
    // d_in[3] attn_mask: deterministic causal triu(k=1) -> computed inline
    const float* tmK  = (const float*)d_in[4];
    const float* tmV  = (const float*)d_in[5];
    const float* posK = (const float*)d_in[6];
    const float* posV = (const float*)d_in[7];
    const float* Wq = (const float*)d_in[8];
    const float* bq = (const float*)d_in[9];
    const float* Wk = (const float*)d_in[10];
    const float* bk = (const float*)d_in[11];
    const float* Wv = (const float*)d_in[12];
    const float* bv = (const float*)d_in[13];

    float* ws   = (float*)d_ws;
    float* Qp   = ws;                  // 819200 floats
    float* Ksum = ws + 819200;         // 819200 floats
    float* Vsum = ws + 2 * 819200;     // 819200 floats
    float* out  = (float*)d_out;

    hipLaunchKernelGGL(proj_kernel, dim3(400), dim3(256), 0, stream,
                       queries, keys, posK, posV, Wq, bq, Wk, bk, Wv, bv,
                       Qp, Ksum, Vsum);
    hipLaunchKernelGGL(attn_kernel, dim3(3200), dim3(256), 0, stream,
                       Qp, Ksum, Vsum, tmK, tmV, tmask, out);
}

// Round 2
// 303.765 us; speedup vs baseline: 1.0801x; 1.0801x over previous
//
#include <hip/hip_runtime.h>
#include <math.h>

// B=16, L=200, H=256, heads=4, d=64
#define LQ 200
#define HDIM 256

// ---------------- Kernel 1: projections + pos-bias folding -------------------
// Q    = (queries @ Wq.T + bq) * 0.125   (scale folded in)
// Ksum = keys    @ Wk.T + bk + abs_pos_K
// Vsum = keys    @ Wv.T + bv + abs_pos_V
__global__ __launch_bounds__(256) void proj_kernel(
    const float* __restrict__ queries, const float* __restrict__ keys,
    const float* __restrict__ posK, const float* __restrict__ posV,
    const float* __restrict__ Wq, const float* __restrict__ bq,
    const float* __restrict__ Wk, const float* __restrict__ bk,
    const float* __restrict__ Wv, const float* __restrict__ bv,
    float* __restrict__ Qp, float* __restrict__ Ksum, float* __restrict__ Vsum)
{
    __shared__ float qrow[8][HDIM];
    __shared__ float krow[8][HDIM];
    const int t = threadIdx.x;
    const int blk = blockIdx.x;                 // 0..399
    const size_t base = (size_t)blk * 8 * HDIM;

    #pragma unroll
    for (int i = 0; i < 2; ++i) {
        int idx = i * 1024 + t * 4;
        *(float4*)&qrow[0][idx] = *(const float4*)&queries[base + idx];
        *(float4*)&krow[0][idx] = *(const float4*)&keys[base + idx];
    }
    __syncthreads();

    float accQ[8], accK[8], accV[8];
    #pragma unroll
    for (int r = 0; r < 8; ++r) { accQ[r] = 0.f; accK[r] = 0.f; accV[r] = 0.f; }

    const float4* wqp = (const float4*)&Wq[t * HDIM];
    const float4* wkp = (const float4*)&Wk[t * HDIM];
    const float4* wvp = (const float4*)&Wv[t * HDIM];

    for (int k4 = 0; k4 < HDIM / 4; ++k4) {
        float4 wq = wqp[k4], wk = wkp[k4], wv = wvp[k4];
        #pragma unroll
        for (int r = 0; r < 8; ++r) {
            float4 qv = *(const float4*)&qrow[r][k4 * 4];
            float4 kv = *(const float4*)&krow[r][k4 * 4];
            accQ[r] += qv.x * wq.x + qv.y * wq.y + qv.z * wq.z + qv.w * wq.w;
            accK[r] += kv.x * wk.x + kv.y * wk.y + kv.z * wk.z + kv.w * wk.w;
            accV[r] += kv.x * wv.x + kv.y * wv.y + kv.z * wv.z + kv.w * wv.w;
        }
    }

    const float bqv = bq[t], bkv = bk[t], bvv = bv[t];
    #pragma unroll
    for (int r = 0; r < 8; ++r) {
        size_t row = (size_t)blk * 8 + r;
        Qp[row * HDIM + t]   = (accQ[r] + bqv) * 0.125f;  // 1/sqrt(64) folded
        Ksum[row * HDIM + t] = accK[r] + bkv + posK[row * HDIM + t];
        Vsum[row * HDIM + t] = accV[r] + bvv + posV[row * HDIM + t];
    }
}

// ---------------- Kernel 2: fused single-pass attention ---------------------
// One block per (b,l); 4 waves; wave w handles keys m = w, w+4, ...
// Lane ln: head h = ln>>4, channels c = ln*4 .. ln*4+3 of the H=256 row.
// Per m: stream tmK+tmV rows together, score via 4-step shfl_xor reduce
// (all 16 head-lanes get the sum), e = exp(s) (no max-subtract: |s| <~ 8),
// online-accumulate e*(Vsum+tmV) and S. Causal rows skip m>l entirely
// (A exactly 0 there); time-masked rows use e=1 for all 200 m (exact
// uniform softmax). Normalize at the end; cross-wave combine via LDS.
__global__ __launch_bounds__(256) void attn_fused(
    const float* __restrict__ Qp, const float* __restrict__ Ksum,
    const float* __restrict__ Vsum, const float* __restrict__ tmK,
    const float* __restrict__ tmV, const int* __restrict__ tmask,
    float* __restrict__ out)
{
    __shared__ float outp[4][HDIM];   // per-wave output partials
    __shared__ float Ssh[4][4];       // per-wave, per-head softmax denoms

    const int t = threadIdx.x;
    const int w = t >> 6;
    const int ln = t & 63;
    const int h = ln >> 4;
    const int c = ln * 4;
    const int blk = blockIdx.x;       // b*200 + l
    const int b = blk / LQ;
    const int l = blk - b * LQ;

    const float* tmK_row = tmK + (size_t)blk * (LQ * HDIM);
    const float* tmV_row = tmV + (size_t)blk * (LQ * HDIM);
    const float* Ks_b = Ksum + (size_t)b * (LQ * HDIM);
    const float* Vs_b = Vsum + (size_t)b * (LQ * HDIM);
    const bool rowmask = (tmask[blk] != 0);
    const int mlim = rowmask ? LQ : (l + 1);  // exact: A[m]=0 for m>l otherwise

    const float4 Q4 = *(const float4*)&Qp[(size_t)blk * HDIM + c];

    float4 acc = {0.f, 0.f, 0.f, 0.f};
    float S = 0.f;

    #pragma unroll 2
    for (int m = w; m < mlim; m += 4) {
        const size_t off = (size_t)m * HDIM + c;
        const float4 k1 = *(const float4*)&tmK_row[off];
        const float4 k2 = *(const float4*)&Ks_b[off];
        const float4 v1 = *(const float4*)&tmV_row[off];
        const float4 v2 = *(const float4*)&Vs_b[off];
        float p = Q4.x * (k1.x + k2.x) + Q4.y * (k1.y + k2.y)
                + Q4.z * (k1.z + k2.z) + Q4.w * (k1.w + k2.w);
        p += __shfl_xor(p, 1);
        p += __shfl_xor(p, 2);
        p += __shfl_xor(p, 4);
        p += __shfl_xor(p, 8);   // all 16 lanes of the head hold the full dot
        const float e = rowmask ? 1.0f : __expf(p);
        acc.x += e * (v1.x + v2.x);
        acc.y += e * (v1.y + v2.y);
        acc.z += e * (v1.z + v2.z);
        acc.w += e * (v1.w + v2.w);
        S += e;   // identical across the head's 16 lanes
    }

    *(float4*)&outp[w][c] = acc;
    if ((ln & 15) == 0) Ssh[w][h] = S;
    __syncthreads();

    const int hh = t >> 6;   // head owning output channel t
    const float Stot = Ssh[0][hh] + Ssh[1][hh] + Ssh[2][hh] + Ssh[3][hh];
    out[(size_t)blk * HDIM + t] =
        (outp[0][t] + outp[1][t] + outp[2][t] + outp[3][t]) / Stot;
}

// ---------------- launch ----------------------------------------------------
extern "C" void kernel_launch(void* const* d_in, const int* in_sizes, int n_in,
                              void* d_out, int out_size, void* d_ws, size_t ws_size,
                              hipStream_t stream) {
    const float* queries = (const float*)d_in[0];
    const float* keys    = (const float*)d_in[1];
    const int*   tmask   = (const int*)d_in[2];
    // d_in[3] attn_mask: deterministic causal triu(k=1) -> handled analytically
    const float* tmK  = (const float*)d_in[4];
    const float* tmV  = (const float*)d_in[5];
    const float* posK = (const float*)d_in[6];
    const float* posV = (const float*)d_in[7];
    const float* Wq = (const float*)d_in[8];
    const float* bq = (const float*)d_in[9];
    const float* Wk = (const float*)d_in[10];
    const float* bk = (const float*)d_in[11];
    const float* Wv = (const float*)d_in[12];
    const float* bv = (const float*)d_in[13];

    float* ws   = (float*)d_ws;
    float* Qp   = ws;                  // 819200 floats
    float* Ksum = ws + 819200;         // 819200 floats
    float* Vsum = ws + 2 * 819200;     // 819200 floats
    float* out  = (float*)d_out;

    hipLaunchKernelGGL(proj_kernel, dim3(400), dim3(256), 0, stream,
                       queries, keys, posK, posV, Wq, bq, Wk, bk, Wv, bv,
                       Qp, Ksum, Vsum);
    hipLaunchKernelGGL(attn_fused, dim3(3200), dim3(256), 0, stream,
                       Qp, Ksum, Vsum, tmK, tmV, tmask, out);
}

// Round 3
// 237.550 us; speedup vs baseline: 1.3811x; 1.2787x over previous
//
#include <hip/hip_runtime.h>
#include <math.h>

// B=16, L=200, H=256, heads=4, d=64
#define LQ 200
#define HDIM 256

// 16-lane (within-row-of-16) sum reduction via DPP adds on the VALU pipe.
// After the 4 steps every lane of each 16-lane group holds the group sum.
template <int CTRL>
__device__ __forceinline__ float dpp_add_step(float x) {
    int y = __builtin_amdgcn_update_dpp(0, __float_as_int(x), CTRL, 0xF, 0xF, true);
    return x + __int_as_float(y);
}
__device__ __forceinline__ float reduce16(float x) {
    x = dpp_add_step<0xB1>(x);   // quad_perm [1,0,3,2]  : xor 1
    x = dpp_add_step<0x4E>(x);   // quad_perm [2,3,0,1]  : xor 2
    x = dpp_add_step<0x141>(x);  // row_half_mirror      : crosses 4-boundary
    x = dpp_add_step<0x140>(x);  // row_mirror           : crosses 8-boundary
    return x;
}

// ---------------- Kernel 1: projections + pos-bias folding -------------------
// Q    = (queries @ Wq.T + bq) * 0.125   (1/sqrt(64) folded)
// Ksum = keys    @ Wk.T + bk + abs_pos_K
// Vsum = keys    @ Wv.T + bv + abs_pos_V
__global__ __launch_bounds__(256) void proj_kernel(
    const float* __restrict__ queries, const float* __restrict__ keys,
    const float* __restrict__ posK, const float* __restrict__ posV,
    const float* __restrict__ Wq, const float* __restrict__ bq,
    const float* __restrict__ Wk, const float* __restrict__ bk,
    const float* __restrict__ Wv, const float* __restrict__ bv,
    float* __restrict__ Qp, float* __restrict__ Ksum, float* __restrict__ Vsum)
{
    __shared__ float qrow[8][HDIM];
    __shared__ float krow[8][HDIM];
    const int t = threadIdx.x;
    const int blk = blockIdx.x;                 // 0..399
    const size_t base = (size_t)blk * 8 * HDIM;

    #pragma unroll
    for (int i = 0; i < 2; ++i) {
        int idx = i * 1024 + t * 4;
        *(float4*)&qrow[0][idx] = *(const float4*)&queries[base + idx];
        *(float4*)&krow[0][idx] = *(const float4*)&keys[base + idx];
    }
    __syncthreads();

    float accQ[8], accK[8], accV[8];
    #pragma unroll
    for (int r = 0; r < 8; ++r) { accQ[r] = 0.f; accK[r] = 0.f; accV[r] = 0.f; }

    const float4* wqp = (const float4*)&Wq[t * HDIM];
    const float4* wkp = (const float4*)&Wk[t * HDIM];
    const float4* wvp = (const float4*)&Wv[t * HDIM];

    for (int k4 = 0; k4 < HDIM / 4; ++k4) {
        float4 wq = wqp[k4], wk = wkp[k4], wv = wvp[k4];
        #pragma unroll
        for (int r = 0; r < 8; ++r) {
            float4 qv = *(const float4*)&qrow[r][k4 * 4];
            float4 kv = *(const float4*)&krow[r][k4 * 4];
            accQ[r] += qv.x * wq.x + qv.y * wq.y + qv.z * wq.z + qv.w * wq.w;
            accK[r] += kv.x * wk.x + kv.y * wk.y + kv.z * wk.z + kv.w * wk.w;
            accV[r] += kv.x * wv.x + kv.y * wv.y + kv.z * wv.z + kv.w * wv.w;
        }
    }

    const float bqv = bq[t], bkv = bk[t], bvv = bv[t];
    #pragma unroll
    for (int r = 0; r < 8; ++r) {
        size_t row = (size_t)blk * 8 + r;
        Qp[row * HDIM + t]   = (accQ[r] + bqv) * 0.125f;
        Ksum[row * HDIM + t] = accK[r] + bkv + posK[row * HDIM + t];
        Vsum[row * HDIM + t] = accV[r] + bvv + posV[row * HDIM + t];
    }
}

// ---------------- Kernel 2: fused single-pass attention ---------------------
// One block per (b,l); 4 waves; wave w handles keys m == w (mod 4).
// Lane ln: head h = ln>>4, channels c = ln*4..ln*4+3.
// time-masked rows: A is exactly uniform 1/200 -> skip tmK + scores entirely,
//   just average (Vsum + tmV).
// causal rows: A[m]=0 exactly for m>l -> loop m<=l only. Score reduce via
//   DPP adds (VALU), exp without max-subtract (|s| <~ 8), online accumulate.
__global__ __launch_bounds__(256) void attn_fused(
    const float* __restrict__ Qp, const float* __restrict__ Ksum,
    const float* __restrict__ Vsum, const float* __restrict__ tmK,
    const float* __restrict__ tmV, const int* __restrict__ tmask,
    float* __restrict__ out)
{
    __shared__ float outp[4][HDIM];   // per-wave output partials
    __shared__ float Ssh[4][4];       // per-wave, per-head softmax denoms

    const int t = threadIdx.x;
    const int w = t >> 6;
    const int ln = t & 63;
    const int h = ln >> 4;
    const int c = ln * 4;
    const int blk = blockIdx.x;       // b*200 + l
    const int b = blk / LQ;
    const int l = blk - b * LQ;

    const float* tmV_row = tmV + (size_t)blk * (LQ * HDIM);
    const float* Vs_b = Vsum + (size_t)b * (LQ * HDIM);
    const bool rowmask = (tmask[blk] != 0);

    float4 acc = {0.f, 0.f, 0.f, 0.f};

    if (rowmask) {
        // ---- exact-uniform row: out = (1/200) * sum_m (Vsum[m] + tmV[m]) ----
        for (int m = w; m < LQ; m += 8) {       // pairs (m, m+4); 200%8==0
            const size_t o0 = (size_t)m * HDIM + c;
            const size_t o1 = (size_t)(m + 4) * HDIM + c;
            const float4 a0 = *(const float4*)&tmV_row[o0];
            const float4 b0 = *(const float4*)&Vs_b[o0];
            const float4 a1 = *(const float4*)&tmV_row[o1];
            const float4 b1 = *(const float4*)&Vs_b[o1];
            acc.x += (a0.x + b0.x) + (a1.x + b1.x);
            acc.y += (a0.y + b0.y) + (a1.y + b1.y);
            acc.z += (a0.z + b0.z) + (a1.z + b1.z);
            acc.w += (a0.w + b0.w) + (a1.w + b1.w);
        }
        *(float4*)&outp[w][c] = acc;
        __syncthreads();
        out[(size_t)blk * HDIM + t] =
            (outp[0][t] + outp[1][t] + outp[2][t] + outp[3][t]) * (1.0f / LQ);
    } else {
        // ---- causal row: m in [0, l] ----
        const float* tmK_row = tmK + (size_t)blk * (LQ * HDIM);
        const float* Ks_b = Ksum + (size_t)b * (LQ * HDIM);
        const float4 Q4 = *(const float4*)&Qp[(size_t)blk * HDIM + c];
        const int mlim = l + 1;
        float S = 0.f;

        int m = w;
        for (; m + 4 < mlim; m += 8) {
            const size_t o0 = (size_t)m * HDIM + c;
            const size_t o1 = (size_t)(m + 4) * HDIM + c;
            const float4 k10 = *(const float4*)&tmK_row[o0];
            const float4 k20 = *(const float4*)&Ks_b[o0];
            const float4 v10 = *(const float4*)&tmV_row[o0];
            const float4 v20 = *(const float4*)&Vs_b[o0];
            const float4 k11 = *(const float4*)&tmK_row[o1];
            const float4 k21 = *(const float4*)&Ks_b[o1];
            const float4 v11 = *(const float4*)&tmV_row[o1];
            const float4 v21 = *(const float4*)&Vs_b[o1];
            float p0 = Q4.x * (k10.x + k20.x) + Q4.y * (k10.y + k20.y)
                     + Q4.z * (k10.z + k20.z) + Q4.w * (k10.w + k20.w);
            float p1 = Q4.x * (k11.x + k21.x) + Q4.y * (k11.y + k21.y)
                     + Q4.z * (k11.z + k21.z) + Q4.w * (k11.w + k21.w);
            p0 = reduce16(p0);
            p1 = reduce16(p1);
            const float e0 = __expf(p0);
            const float e1 = __expf(p1);
            acc.x += e0 * (v10.x + v20.x) + e1 * (v11.x + v21.x);
            acc.y += e0 * (v10.y + v20.y) + e1 * (v11.y + v21.y);
            acc.z += e0 * (v10.z + v20.z) + e1 * (v11.z + v21.z);
            acc.w += e0 * (v10.w + v20.w) + e1 * (v11.w + v21.w);
            S += e0 + e1;
        }
        if (m < mlim) {
            const size_t o0 = (size_t)m * HDIM + c;
            const float4 k10 = *(const float4*)&tmK_row[o0];
            const float4 k20 = *(const float4*)&Ks_b[o0];
            const float4 v10 = *(const float4*)&tmV_row[o0];
            const float4 v20 = *(const float4*)&Vs_b[o0];
            float p0 = Q4.x * (k10.x + k20.x) + Q4.y * (k10.y + k20.y)
                     + Q4.z * (k10.z + k20.z) + Q4.w * (k10.w + k20.w);
            p0 = reduce16(p0);
            const float e0 = __expf(p0);
            acc.x += e0 * (v10.x + v20.x);
            acc.y += e0 * (v10.y + v20.y);
            acc.z += e0 * (v10.z + v20.z);
            acc.w += e0 * (v10.w + v20.w);
            S += e0;
        }

        *(float4*)&outp[w][c] = acc;
        if ((ln & 15) == 0) Ssh[w][h] = S;
        __syncthreads();

        const int hh = t >> 6;   // head owning output channel t
        const float Stot = Ssh[0][hh] + Ssh[1][hh] + Ssh[2][hh] + Ssh[3][hh];
        out[(size_t)blk * HDIM + t] =
            (outp[0][t] + outp[1][t] + outp[2][t] + outp[3][t]) / Stot;
    }
}

// ---------------- launch ----------------------------------------------------
extern "C" void kernel_launch(void* const* d_in, const int* in_sizes, int n_in,
                              void* d_out, int out_size, void* d_ws, size_t ws_size,
                              hipStream_t stream) {
    const float* queries = (const float*)d_in[0];
    const float* keys    = (const float*)d_in[1];
    const int*   tmask   = (const int*)d_in[2];
    // d_in[3] attn_mask: deterministic causal triu(k=1) -> handled analytically
    const float* tmK  = (const float*)d_in[4];
    const float* tmV  = (const float*)d_in[5];
    const float* posK = (const float*)d_in[6];
    const float* posV = (const float*)d_in[7];
    const float* Wq = (const float*)d_in[8];
    const float* bq = (const float*)d_in[9];
    const float* Wk = (const float*)d_in[10];
    const float* bk = (const float*)d_in[11];
    const float* Wv = (const float*)d_in[12];
    const float* bv = (const float*)d_in[13];

    float* ws   = (float*)d_ws;
    float* Qp   = ws;                  // 819200 floats
    float* Ksum = ws + 819200;         // 819200 floats
    float* Vsum = ws + 2 * 819200;     // 819200 floats
    float* out  = (float*)d_out;

    hipLaunchKernelGGL(proj_kernel, dim3(400), dim3(256), 0, stream,
                       queries, keys, posK, posV, Wq, bq, Wk, bk, Wv, bv,
                       Qp, Ksum, Vsum);
    hipLaunchKernelGGL(attn_fused, dim3(3200), dim3(256), 0, stream,
                       Qp, Ksum, Vsum, tmK, tmV, tmask, out);
}